// Round 1
// baseline (129.720 us; speedup 1.0000x reference)
//
#include <hip/hip_runtime.h>
#include <math.h>

typedef __attribute__((ext_vector_type(8))) short short8;
typedef __attribute__((ext_vector_type(4))) float float4v;

#define GH_ 256
#define GW_ 256
#define H_  128
#define W_  128
#define C_  64
#define OC_ 64
#define NB_ 4

static __device__ __forceinline__ unsigned short f2bf(float f) {
    union { float f; unsigned int u; } v; v.f = f;
    unsigned int u = v.u;
    unsigned int r = u + 0x7FFFu + ((u >> 16) & 1u);   // round-to-nearest-even
    return (unsigned short)(r >> 16);
}

// x[b][c][ih][iw] fp32  ->  xbf[b][ih][iw][c] bf16  (c contiguous for B-fragments)
__global__ __launch_bounds__(256) void prep_x(const float* __restrict__ x,
                                              unsigned short* __restrict__ xbf) {
    int half = blockIdx.x, ih = blockIdx.y, b = blockIdx.z;
    int tid = threadIdx.x;
    __shared__ float xl[C_][65];
    int iw0 = half * 64;
    for (int i = tid; i < C_ * 64; i += 256) {
        int c = i >> 6, iw = i & 63;
        xl[c][iw] = x[(((b * C_ + c) * H_) + ih) * W_ + iw0 + iw];
    }
    __syncthreads();
    for (int i = tid; i < 64 * 32; i += 256) {
        int iw = i >> 5, cp = i & 31;
        unsigned int lo = f2bf(xl[2 * cp][iw]);
        unsigned int hi = f2bf(xl[2 * cp + 1][iw]);
        unsigned int* dst = (unsigned int*)(xbf +
            ((size_t)((b * H_ + ih) * W_ + iw0 + iw)) * C_);
        dst[cp] = lo | (hi << 16);
    }
}

// weight[c][o][kh][kw] fp32 -> wtb[t=kh*3+kw][o][c] bf16 (A-side, k=c contiguous)
__global__ __launch_bounds__(256) void prep_w(const float* __restrict__ w,
                                              unsigned short* __restrict__ wtb) {
    int i = blockIdx.x * 256 + threadIdx.x;     // over 9*64*64
    if (i >= 9 * OC_ * C_) return;
    int c = i & 63, o = (i >> 6) & 63, t = i >> 12;
    int kh = t / 3, kw = t - kh * 3;
    wtb[i] = f2bf(w[((c * OC_ + o) * 3 + kh) * 3 + kw]);
}

// One block: (b, parity class, yp-pair). M = o (64), N = 256 pixels (2 class rows x 128),
// per-tap K=64 GEMM via mfma_f32_16x16x32_bf16, kern applied per-tap in epilogue.
__global__ __launch_bounds__(256) void pac_main(
    const unsigned short* __restrict__ xbf,
    const float* __restrict__ guide,
    const unsigned short* __restrict__ wtb,
    const float* __restrict__ bias,
    float* __restrict__ out)
{
    const int ypair = blockIdx.x;   // 0..63
    const int cls   = blockIdx.y;   // 0..3
    const int b     = blockIdx.z;   // 0..3
    const int hp = cls >> 1, wp = cls & 1;
    const int ntap = (1 + hp) * (1 + wp);
    const int tid = threadIdx.x;

    __shared__ float klds[4][256];

    // ---- gaussian affinity kern per (tap, pixel) ----
    for (int i = tid; i < ntap * 256; i += 256) {
        int px = i & 255;
        int tapi = i >> 8;
        int r = tapi >> wp, q = tapi & wp;       // ntq = 1+wp in {1,2}
        int py = px >> 7, xp = px & 127;
        int yp = ypair * 2 + py;
        int h = 2 * yp + hp, w = 2 * xp + wp;
        int rr = yp + r, cl = xp + q;
        float kv = 0.f;
        if (rr < H_ && cl < W_) {
            int hh = rr * 2, ww = cl * 2;        // guide neighbor, always in-bounds
            const float* gb = guide + (size_t)b * 3 * GH_ * GW_;
            float s = 0.f;
            #pragma unroll
            for (int g = 0; g < 3; ++g) {
                float gn = gb[(g * GH_ + hh) * GW_ + ww];
                float gc = gb[(g * GH_ + h) * GW_ + w];
                float d = gn - gc;
                s += d * d;
            }
            kv = __expf(-0.5f * s);
        }
        klds[tapi][px] = kv;
    }
    __syncthreads();

    const int wave = tid >> 6, lane = tid & 63;
    const int l16 = lane & 15, qk = lane >> 4;
    const int py  = wave >> 1;             // waves 0,1 -> row 0 ; 2,3 -> row 1
    const int xpb = (wave & 1) * 64;
    const int yp  = ypair * 2 + py;
    const int h   = 2 * yp + hp;

    float acc[4][4][4];
    #pragma unroll
    for (int mf = 0; mf < 4; ++mf)
        #pragma unroll
        for (int nf = 0; nf < 4; ++nf)
            #pragma unroll
            for (int e = 0; e < 4; ++e) acc[mf][nf][e] = 0.f;

    for (int tapi = 0; tapi < ntap; ++tapi) {
        int r = tapi >> wp, q = tapi & wp;
        int kh = hp ? 2 * r : 1;
        int kw = wp ? 2 * q : 1;
        int t = kh * 3 + kw;
        int row = yp + r; if (row > H_ - 1) row = H_ - 1;   // kern==0 kills clamped taps

        // A fragments: A[m=o][k=c] = wtb[t][o][c]; lane holds A[m=l16+16mf][k=qk*8+j]
        const short8* wbase = (const short8*)(wtb + (size_t)t * OC_ * C_);
        short8 af[4][2];
        #pragma unroll
        for (int mf = 0; mf < 4; ++mf) {
            int o = mf * 16 + l16;
            af[mf][0] = wbase[(o * C_ + qk * 8) >> 3];
            af[mf][1] = wbase[(o * C_ + 32 + qk * 8) >> 3];
        }

        #pragma unroll
        for (int nf = 0; nf < 4; ++nf) {
            int xp = xpb + nf * 16 + l16;
            int col = xp + q; if (col > W_ - 1) col = W_ - 1;
            // B fragments: B[k=c][n=px] from xbf[row][col][c] (c contiguous)
            const short8* xb = (const short8*)(xbf +
                ((size_t)((b * H_ + row) * W_ + col)) * C_);
            short8 bf0 = xb[qk];
            short8 bf1 = xb[4 + qk];
            float kv = klds[tapi][wave * 64 + nf * 16 + l16];
            #pragma unroll
            for (int mf = 0; mf < 4; ++mf) {
                float4v d = {0.f, 0.f, 0.f, 0.f};
                d = __builtin_amdgcn_mfma_f32_16x16x32_bf16(af[mf][0], bf0, d, 0, 0, 0);
                d = __builtin_amdgcn_mfma_f32_16x16x32_bf16(af[mf][1], bf1, d, 0, 0, 0);
                #pragma unroll
                for (int e = 0; e < 4; ++e)
                    acc[mf][nf][e] += kv * d[e];
            }
        }
    }

    // ---- epilogue: bias + scattered store (out[b][o][h][w], w stride 2) ----
    float bv[4][4];
    #pragma unroll
    for (int mf = 0; mf < 4; ++mf)
        #pragma unroll
        for (int e = 0; e < 4; ++e)
            bv[mf][e] = bias[mf * 16 + qk * 4 + e];

    #pragma unroll
    for (int mf = 0; mf < 4; ++mf)
        #pragma unroll
        for (int nf = 0; nf < 4; ++nf) {
            int xp = xpb + nf * 16 + l16;
            int w = 2 * xp + wp;
            #pragma unroll
            for (int e = 0; e < 4; ++e) {
                int o = mf * 16 + qk * 4 + e;
                out[(((size_t)b * OC_ + o) * GH_ + h) * GW_ + w] =
                    acc[mf][nf][e] + bv[mf][e];
            }
        }
}

extern "C" void kernel_launch(void* const* d_in, const int* in_sizes, int n_in,
                              void* d_out, int out_size, void* d_ws, size_t ws_size,
                              hipStream_t stream) {
    const float* x     = (const float*)d_in[0];
    const float* guide = (const float*)d_in[1];
    const float* wgt   = (const float*)d_in[2];
    const float* bias  = (const float*)d_in[3];
    float* out = (float*)d_out;

    unsigned short* xbf = (unsigned short*)d_ws;                   // 8.39 MB
    unsigned short* wtb = xbf + (size_t)NB_ * H_ * W_ * C_;        // +72 KB

    prep_x<<<dim3(2, 128, 4), 256, 0, stream>>>(x, xbf);
    prep_w<<<dim3((9 * 64 * 64 + 255) / 256), 256, 0, stream>>>(wgt, wtb);
    pac_main<<<dim3(64, 4, 4), 256, 0, stream>>>(xbf, guide, wtb, bias, out);
}

// Round 2
// 120.924 us; speedup vs baseline: 1.0727x; 1.0727x over previous
//
#include <hip/hip_runtime.h>
#include <math.h>

typedef __attribute__((ext_vector_type(8))) short short8;
typedef __attribute__((ext_vector_type(4))) float float4v;

#define GH_ 256
#define GW_ 256
#define H_  128
#define W_  128
#define C_  64
#define OC_ 64
#define NB_ 4

static __device__ __forceinline__ unsigned short f2bf(float f) {
    union { float f; unsigned int u; } v; v.f = f;
    unsigned int u = v.u;
    unsigned int r = u + 0x7FFFu + ((u >> 16) & 1u);   // round-to-nearest-even
    return (unsigned short)(r >> 16);
}

// Fused prep:
//  z<4 : x[b][c][ih][iw] fp32 -> xbf[b][ih][iw][c] bf16 (c contiguous, B-side)
//  z==4: weight[c][o][kh][kw] fp32 -> wtb[t=kh*3+kw][o][c] bf16 (A-side)
__global__ __launch_bounds__(256) void prep(const float* __restrict__ x,
                                            const float* __restrict__ w,
                                            unsigned short* __restrict__ xbf,
                                            unsigned short* __restrict__ wtb) {
    int b = blockIdx.z;
    int tid = threadIdx.x;
    if (b == 4) {
        int flat = (blockIdx.y * 2 + blockIdx.x) * 256 + tid;
        if (flat < 9 * OC_ * C_) {
            int c = flat & 63, o = (flat >> 6) & 63, t = flat >> 12;
            int kh = t / 3, kw = t - kh * 3;
            wtb[flat] = f2bf(w[((c * OC_ + o) * 3 + kh) * 3 + kw]);
        }
        return;
    }
    int half = blockIdx.x, ih = blockIdx.y;
    __shared__ float xl[C_][65];
    int iw0 = half * 64;
    for (int i = tid; i < C_ * 64; i += 256) {
        int c = i >> 6, iw = i & 63;
        xl[c][iw] = x[(((b * C_ + c) * H_) + ih) * W_ + iw0 + iw];
    }
    __syncthreads();
    for (int i = tid; i < 64 * 32; i += 256) {
        int iw = i >> 5, cp = i & 31;
        unsigned int lo = f2bf(xl[2 * cp][iw]);
        unsigned int hi = f2bf(xl[2 * cp + 1][iw]);
        unsigned int* dst = (unsigned int*)(xbf +
            ((size_t)((b * H_ + ih) * W_ + iw0 + iw)) * C_);
        dst[cp] = lo | (hi << 16);
    }
}

// Block = (ypair, hp, b): 2 output rows (py=0,1), ALL 256 columns (both w-parities).
// 512 threads = 8 waves = (oh, py, xh). Each lane accumulates both parities for its
// pixel column and stores a contiguous float2 at w=2*xp -> full-line writebacks.
__global__ __launch_bounds__(512, 2) void pac_main(
    const unsigned short* __restrict__ xbf,
    const float* __restrict__ guide,
    const unsigned short* __restrict__ wtb,
    const float* __restrict__ bias,
    float* __restrict__ out)
{
    const int ypair = blockIdx.x;   // 0..63
    const int hp    = blockIdx.y;   // 0..1
    const int b     = blockIdx.z;   // 0..3
    const int tid = threadIdx.x;
    const int ntr = 1 + hp;         // taps along r
    const int nslot = 3 * ntr;      // wp0: ntr slots, wp1: 2*ntr slots

    __shared__ float klds[6][2][128];   // [slot][py][xp]

    // ---- gaussian affinity kern per (slot, py, xp) ----
    for (int i = tid; i < nslot * 256; i += 512) {
        int px = i & 255, slot = i >> 8;
        int py = px >> 7, xp = px & 127;
        int wp, r, q;
        if (slot < ntr) { wp = 0; r = slot; q = 0; }
        else { int s = slot - ntr; wp = 1; r = s >> 1; q = s & 1; }
        int yp = ypair * 2 + py;
        int h = 2 * yp + hp, w = 2 * xp + wp;
        int rr = yp + r, cl = xp + q;
        float kv = 0.f;
        if (rr < H_ && cl < W_) {
            int hh = rr * 2, ww = cl * 2;        // guide neighbor, always in-bounds
            const float* gb = guide + (size_t)b * 3 * GH_ * GW_;
            float s2 = 0.f;
            #pragma unroll
            for (int g = 0; g < 3; ++g) {
                float d = gb[(g * GH_ + hh) * GW_ + ww] - gb[(g * GH_ + h) * GW_ + w];
                s2 += d * d;
            }
            kv = __expf(-0.5f * s2);
        }
        klds[slot][py][xp] = kv;
    }
    __syncthreads();

    const int wave = tid >> 6, lane = tid & 63;
    const int l16 = lane & 15, qk = lane >> 4;
    const int oh  = wave & 1;              // o half: 0..1 -> obase
    const int py  = (wave >> 1) & 1;
    const int xh  = wave >> 2;             // x half: 0..1
    const int obase = oh * 32;
    const int xpb   = xh * 64;
    const int yp = ypair * 2 + py;
    const int h  = 2 * yp + hp;

    float acc0[2][4][4];   // wp=0 (w = 2xp)
    float acc1[2][4][4];   // wp=1 (w = 2xp+1)
    #pragma unroll
    for (int mf = 0; mf < 2; ++mf)
        #pragma unroll
        for (int nf = 0; nf < 4; ++nf)
            #pragma unroll
            for (int e = 0; e < 4; ++e) { acc0[mf][nf][e] = 0.f; acc1[mf][nf][e] = 0.f; }

    for (int r = 0; r <= hp; ++r) {
        int kh = hp ? 2 * r : 1;
        int row = yp + r; if (row > H_ - 1) row = H_ - 1;   // kern==0 kills clamped taps
        int s_c = r;                  // wp0, kw=1
        int s_l = ntr + 2 * r;        // wp1, q=0, kw=0
        int s_r = ntr + 2 * r + 1;    // wp1, q=1, kw=2

        // A fragments for kw=0,1,2 at this kh: A[m=o][k=c] = wtb[t][o][c]
        short8 af[3][2][2];
        #pragma unroll
        for (int kw3 = 0; kw3 < 3; ++kw3) {
            const short8* wbase = (const short8*)(wtb + (size_t)(kh * 3 + kw3) * OC_ * C_);
            #pragma unroll
            for (int mf = 0; mf < 2; ++mf) {
                int o = obase + mf * 16 + l16;
                af[kw3][mf][0] = wbase[(o * C_ + qk * 8) >> 3];
                af[kw3][mf][1] = wbase[(o * C_ + 32 + qk * 8) >> 3];
            }
        }

        #pragma unroll
        for (int nf = 0; nf < 4; ++nf) {
            int xp = xpb + nf * 16 + l16;
            int col0 = xp;
            int col1 = xp + 1; if (col1 > W_ - 1) col1 = W_ - 1;
            const short8* xb0 = (const short8*)(xbf +
                ((size_t)((b * H_ + row) * W_ + col0)) * C_);
            const short8* xb1 = (const short8*)(xbf +
                ((size_t)((b * H_ + row) * W_ + col1)) * C_);
            short8 b0a = xb0[qk],     b0b = xb0[4 + qk];
            short8 b1a = xb1[qk],     b1b = xb1[4 + qk];
            float kc = klds[s_c][py][xp];
            float kl = klds[s_l][py][xp];
            float kr = klds[s_r][py][xp];
            #pragma unroll
            for (int mf = 0; mf < 2; ++mf) {
                float4v d;
                d = (float4v){0.f, 0.f, 0.f, 0.f};
                d = __builtin_amdgcn_mfma_f32_16x16x32_bf16(af[1][mf][0], b0a, d, 0, 0, 0);
                d = __builtin_amdgcn_mfma_f32_16x16x32_bf16(af[1][mf][1], b0b, d, 0, 0, 0);
                #pragma unroll
                for (int e = 0; e < 4; ++e) acc0[mf][nf][e] += kc * d[e];
                d = (float4v){0.f, 0.f, 0.f, 0.f};
                d = __builtin_amdgcn_mfma_f32_16x16x32_bf16(af[0][mf][0], b0a, d, 0, 0, 0);
                d = __builtin_amdgcn_mfma_f32_16x16x32_bf16(af[0][mf][1], b0b, d, 0, 0, 0);
                #pragma unroll
                for (int e = 0; e < 4; ++e) acc1[mf][nf][e] += kl * d[e];
                d = (float4v){0.f, 0.f, 0.f, 0.f};
                d = __builtin_amdgcn_mfma_f32_16x16x32_bf16(af[2][mf][0], b1a, d, 0, 0, 0);
                d = __builtin_amdgcn_mfma_f32_16x16x32_bf16(af[2][mf][1], b1b, d, 0, 0, 0);
                #pragma unroll
                for (int e = 0; e < 4; ++e) acc1[mf][nf][e] += kr * d[e];
            }
        }
    }

    // ---- epilogue: bias + contiguous float2 stores ----
    float bv[2][4];
    #pragma unroll
    for (int mf = 0; mf < 2; ++mf)
        #pragma unroll
        for (int e = 0; e < 4; ++e)
            bv[mf][e] = bias[obase + mf * 16 + qk * 4 + e];

    #pragma unroll
    for (int mf = 0; mf < 2; ++mf)
        #pragma unroll
        for (int e = 0; e < 4; ++e) {
            int o = obase + mf * 16 + qk * 4 + e;
            float2* op = (float2*)(out + (((size_t)b * OC_ + o) * GH_ + h) * GW_);
            #pragma unroll
            for (int nf = 0; nf < 4; ++nf) {
                int xp = xpb + nf * 16 + l16;
                float2 v;
                v.x = acc0[mf][nf][e] + bv[mf][e];
                v.y = acc1[mf][nf][e] + bv[mf][e];
                op[xp] = v;
            }
        }
}

extern "C" void kernel_launch(void* const* d_in, const int* in_sizes, int n_in,
                              void* d_out, int out_size, void* d_ws, size_t ws_size,
                              hipStream_t stream) {
    const float* x     = (const float*)d_in[0];
    const float* guide = (const float*)d_in[1];
    const float* wgt   = (const float*)d_in[2];
    const float* bias  = (const float*)d_in[3];
    float* out = (float*)d_out;

    unsigned short* xbf = (unsigned short*)d_ws;                   // 8.39 MB
    unsigned short* wtb = xbf + (size_t)NB_ * H_ * W_ * C_;        // +72 KB

    prep<<<dim3(2, 128, 5), 256, 0, stream>>>(x, wgt, xbf, wtb);
    pac_main<<<dim3(64, 2, 4), 512, 0, stream>>>(xbf, guide, wtb, bias, out);
}